// Round 5
// baseline (317.093 us; speedup 1.0000x reference)
//
#include <hip/hip_runtime.h>
#include <hip/hip_bf16.h>
#include <math.h>

#define N 4096
#define IN_F 256
#define OUT_F 512
#define H 8
#define D 64
#define NEG 0.2f
#define LOG2E 1.44269504f

typedef __attribute__((ext_vector_type(8))) short bf16x8;
typedef __attribute__((ext_vector_type(4))) float f32x4;

__device__ __forceinline__ float leaky(float x) { return fmaxf(x, NEG * x); }

__device__ __forceinline__ unsigned short f2bf(float x) {
    union { float f; unsigned u; } v; v.f = x;
    unsigned r = v.u + 0x7fff + ((v.u >> 16) & 1);  // RNE
    return (unsigned short)(r >> 16);
}

// pack two f32 -> u32 of 2x bf16 (lo=a, hi=b) via compiler intrinsic (RNE).
__device__ __forceinline__ unsigned pk_bf16(float a, float b) {
    __hip_bfloat162 h2 = __float22bfloat162_rn(float2{a, b});
    union { __hip_bfloat162 h; unsigned u; } u; u.h = h2;
    return u.u;
}

// monotone float<->uint map for atomicMax-based float max
__device__ __forceinline__ unsigned fmap(float x) {
    union { float f; unsigned u; } v; v.f = x;
    return (v.u & 0x80000000u) ? ~v.u : (v.u | 0x80000000u);
}
__device__ __forceinline__ float funmap(unsigned m) {
    union { float f; unsigned u; } v;
    v.u = (m & 0x80000000u) ? (m & 0x7fffffffu) : ~m;
    return v.f;
}

// ---- K1: h = inp @ W^T per (i-tile, head). BK=64, register-prefetch double buffer.
// Epilogue: scores s + block-reduced smax + bf16 transpose to hbT[h][d][j].
__global__ __launch_bounds__(256) void k_gemm(const float* __restrict__ inp,
                                              const float* __restrict__ W,
                                              const float* __restrict__ a_left,
                                              unsigned short* __restrict__ hbT,
                                              float* __restrict__ s,
                                              unsigned* __restrict__ smaxU) {
    __shared__ float As[64][69];
    __shared__ float Bs[64][69];
    __shared__ unsigned short h_st[64][72];
    __shared__ float s_red[64];

    const int t = threadIdx.x;
    const int bi = blockIdx.x;
    const int head = blockIdx.y;
    const int ty = t >> 4, tx = t & 15;
    const int lr = t >> 2;            // 0..63 row within tile
    const int cq = (t & 3) * 16;      // k sub-offset

    float4 pa[4], pb[4];
    auto loadrk = [&](int k0) {
        const float* ip = &inp[(size_t)(bi * 64 + lr) * IN_F + k0 + cq];
        const float* wp = &W[(size_t)(head * 64 + lr) * IN_F + k0 + cq];
#pragma unroll
        for (int q = 0; q < 4; ++q) {
            pa[q] = *(const float4*)&ip[q * 4];
            pb[q] = *(const float4*)&wp[q * 4];
        }
    };
    loadrk(0);

    float acc[4][4] = {};
    for (int k0 = 0; k0 < IN_F; k0 += 64) {
        __syncthreads();
#pragma unroll
        for (int q = 0; q < 4; ++q)
#pragma unroll
            for (int j = 0; j < 4; ++j) {
                As[cq + q * 4 + j][lr] = ((const float*)&pa[q])[j];
                Bs[cq + q * 4 + j][lr] = ((const float*)&pb[q])[j];
            }
        __syncthreads();
        if (k0 + 64 < IN_F) loadrk(k0 + 64);  // prefetch next slice, hidden by compute
#pragma unroll
        for (int k = 0; k < 64; ++k) {
            float4 a4 = *(const float4*)&As[k][ty * 4];
            float4 b4 = *(const float4*)&Bs[k][tx * 4];
            float a[4] = {a4.x, a4.y, a4.z, a4.w};
            float b[4] = {b4.x, b4.y, b4.z, b4.w};
#pragma unroll
            for (int r = 0; r < 4; ++r)
#pragma unroll
                for (int c = 0; c < 4; ++c) acc[r][c] = fmaf(a[r], b[c], acc[r][c]);
        }
    }

    // scores: s[head][i] = sum_d h[i][d]*a_left[head][d]
    float aL[4];
#pragma unroll
    for (int c = 0; c < 4; ++c) aL[c] = a_left[head * D + tx * 4 + c];
#pragma unroll
    for (int r = 0; r < 4; ++r) {
        float sp = acc[r][0] * aL[0] + acc[r][1] * aL[1] + acc[r][2] * aL[2] + acc[r][3] * aL[3];
        sp += __shfl_xor(sp, 1); sp += __shfl_xor(sp, 2);
        sp += __shfl_xor(sp, 4); sp += __shfl_xor(sp, 8);
        if (tx == 0) {
            s[head * N + bi * 64 + ty * 4 + r] = sp;
            s_red[ty * 4 + r] = sp;
        }
    }
    __syncthreads();
    if (t < 64) {  // block-level max -> ONE atomic per block
        float m = s_red[t];
        for (int off = 32; off; off >>= 1) m = fmaxf(m, __shfl_down(m, off, 64));
        if (t == 0) atomicMax(&smaxU[head], fmap(m));
    }

    // stage h tile as bf16 and transpose to hbT[head][d][i]
#pragma unroll
    for (int r = 0; r < 4; ++r) {
        ushort4 v;
        v.x = f2bf(acc[r][0]); v.y = f2bf(acc[r][1]);
        v.z = f2bf(acc[r][2]); v.w = f2bf(acc[r][3]);
        *(ushort4*)&h_st[ty * 4 + r][tx * 4] = v;
    }
    __syncthreads();
    {
        const int d = t >> 2, iq = (t & 3) * 16;
        unsigned short us[16];
#pragma unroll
        for (int k = 0; k < 16; ++k) us[k] = h_st[iq + k][d];
        unsigned short* dst = &hbT[((size_t)(head * D + d)) * N + bi * 64 + iq];
#pragma unroll
        for (int q = 0; q < 4; ++q) {
            ushort4 v = {us[q * 4 + 0], us[q * 4 + 1], us[q * 4 + 2], us[q * 4 + 3]};
            *(ushort4*)&dst[q * 4] = v;
        }
    }
}

// ---- K2: per-row max of A
__global__ __launch_bounds__(256) void k_rowmax(const float* __restrict__ A,
                                                float* __restrict__ rmax) {
    int i = blockIdx.x;
    const float* row = &A[(size_t)i * N];
    float m = -1e30f;
    for (int j = threadIdx.x * 4; j < N; j += 256 * 4) {
        float4 v = *(const float4*)&row[j];
        m = fmaxf(fmaxf(fmaxf(m, v.x), fmaxf(v.y, v.z)), v.w);
    }
    for (int off = 32; off; off >>= 1) m = fmaxf(m, __shfl_down(m, off, 64));
    __shared__ float red[4];
    if ((threadIdx.x & 63) == 0) red[threadIdx.x >> 6] = m;
    __syncthreads();
    if (threadIdx.x == 0) rmax[i] = fmaxf(fmaxf(red[0], red[1]), fmaxf(red[2], red[3]));
}

// ---- K3 r5: fused attention, COMPLETE-ROW blocks, zero barriers, zero LDS.
// Grid 256 = i-tiles of 16 rows. Block 512 thr = 8 waves; wave w == head w.
// Each wave computes its head over the block's 16 rows x FULL j (4096):
// no j-split -> no out/Z atomics, no k_norm, no memset(out).
// All operands direct global->register (hbT 4MB is L2/L3-resident; A rows
// shared by the 8 waves via L1; s is a 32B broadcast per quad). Explicit
// 1-step register prefetch of every stream; no __syncthreads anywhere.
__global__ __launch_bounds__(512, 2) void k_attn(const float* __restrict__ A,
                                                 const unsigned short* __restrict__ hbT,
                                                 const float* __restrict__ s,
                                                 const unsigned* __restrict__ smaxU,
                                                 const float* __restrict__ rmax,
                                                 float* __restrict__ out) {
    const int t = threadIdx.x;
    const int i0 = blockIdx.x * 16;
    const int lane = t & 63, head = t >> 6;   // wave == head
    const int quad = lane >> 4, li = lane & 15;
    const int row = i0 + li;                   // P-fragment row for this lane

    // per-row/per-head softmax constants (exp2 domain)
    const float sr = s[head * N + row];
    const float sI = sr * LOG2E;
    const float mb = (leaky(sr + funmap(smaxU[head])) + rmax[row]) * LOG2E;

    // stream pointers (all 16B/32B aligned)
    const float* Ap = &A[(size_t)row * N + quad * 8];
    const float* sp = &s[(size_t)head * N + quad * 8];
    const unsigned short* hp[4];
#pragma unroll
    for (int db = 0; db < 4; ++db)
        hp[db] = &hbT[((size_t)(head * D + db * 16 + li)) * N + quad * 8];

    // prologue: load step 0
    float4 a0 = *(const float4*)&Ap[0], a1 = *(const float4*)&Ap[4];
    float4 s0 = *(const float4*)&sp[0], s1 = *(const float4*)&sp[4];
    bf16x8 b[4];
#pragma unroll
    for (int db = 0; db < 4; ++db) b[db] = *(const bf16x8*)&hp[db][0];

    f32x4 acc[4] = {{0,0,0,0},{0,0,0,0},{0,0,0,0},{0,0,0,0}};
    float zs = 0.f;

#pragma unroll 2
    for (int jt = 0; jt < N; jt += 32) {
        const bool more = (jt + 32 < N);
        // prefetch next 32-j step into shadow regs (no barriers to defeat it)
        float4 na0, na1, ns0, ns1; bf16x8 nb[4];
        if (more) {
            na0 = *(const float4*)&Ap[jt + 32]; na1 = *(const float4*)&Ap[jt + 36];
            ns0 = *(const float4*)&sp[jt + 32]; ns1 = *(const float4*)&sp[jt + 36];
#pragma unroll
            for (int db = 0; db < 4; ++db) nb[db] = *(const bf16x8*)&hp[db][jt + 32];
        }

        float av[8] = {a0.x, a0.y, a0.z, a0.w, a1.x, a1.y, a1.z, a1.w};
        float sv[8] = {s0.x, s0.y, s0.z, s0.w, s1.x, s1.y, s1.z, s1.w};
        union { bf16x8 v; unsigned u[4]; } P;
#pragma unroll
        for (int p = 0; p < 4; ++p) {
            float x0 = sI + sv[2 * p + 0] * LOG2E;
            float x1 = sI + sv[2 * p + 1] * LOG2E;
            float w0 = __builtin_amdgcn_exp2f(fmaxf(x0, NEG * x0) + (av[2 * p + 0] * LOG2E - mb));
            float w1 = __builtin_amdgcn_exp2f(fmaxf(x1, NEG * x1) + (av[2 * p + 1] * LOG2E - mb));
            zs += w0 + w1;
            P.u[p] = pk_bf16(w0, w1);  // lo = even j, hi = odd j (verified)
        }
#pragma unroll
        for (int db = 0; db < 4; ++db)
            acc[db] = __builtin_amdgcn_mfma_f32_16x16x32_bf16(P.v, b[db], acc[db], 0, 0, 0);

        if (more) {
            a0 = na0; a1 = na1; s0 = ns0; s1 = ns1;
#pragma unroll
            for (int db = 0; db < 4; ++db) b[db] = nb[db];
        }
    }

    // Z for row (i0+li): combine the 4 quads' partial sums (same-li lanes)
    zs += __shfl_xor(zs, 16);
    zs += __shfl_xor(zs, 32);

    // normalize + store: C row = quad*4 + r, col = head*64 + db*16 + li
#pragma unroll
    for (int r = 0; r < 4; ++r) {
        float zrow = __shfl(zs, quad * 4 + r, 64);  // lane li==quad*4+r holds full Z
        float inv = 1.0f / zrow;
        float* op = &out[(size_t)(i0 + quad * 4 + r) * OUT_F + head * D];
#pragma unroll
        for (int db = 0; db < 4; ++db) op[db * 16 + li] = acc[db][r] * inv;
    }
}

extern "C" void kernel_launch(void* const* d_in, const int* in_sizes, int n_in,
                              void* d_out, int out_size, void* d_ws, size_t ws_size,
                              hipStream_t stream) {
    const float* inp = (const float*)d_in[0];
    const float* A = (const float*)d_in[1];
    const float* W = (const float*)d_in[2];
    const float* a_left = (const float*)d_in[3];
    float* out = (float*)d_out;

    // ws layout: hbT (4MB) | s (128KB) | smaxU (32B) | rmax (16KB)
    unsigned short* hbT = (unsigned short*)d_ws;
    float* s = (float*)((char*)d_ws + (size_t)H * D * N * 2);
    unsigned* smaxU = (unsigned*)(s + (size_t)H * N);
    float* rmax = (float*)(smaxU + 8);

    hipMemsetAsync(smaxU, 0, 8 * sizeof(unsigned), stream);

    k_gemm<<<dim3(N / 64, H), 256, 0, stream>>>(inp, W, a_left, hbT, s, smaxU);
    k_rowmax<<<dim3(N), 256, 0, stream>>>(A, rmax);
    k_attn<<<dim3(N / 16), 512, 0, stream>>>(A, hbT, s, smaxU, rmax, out);
}

// Round 6
// 265.884 us; speedup vs baseline: 1.1926x; 1.1926x over previous
//
#include <hip/hip_runtime.h>
#include <hip/hip_bf16.h>
#include <math.h>

#define N 4096
#define IN_F 256
#define OUT_F 512
#define H 8
#define D 64
#define NEG 0.2f
#define LOG2E 1.44269504f

typedef __attribute__((ext_vector_type(8))) short bf16x8;
typedef __attribute__((ext_vector_type(4))) float f32x4;

__device__ __forceinline__ float leaky(float x) { return fmaxf(x, NEG * x); }

__device__ __forceinline__ unsigned short f2bf(float x) {
    union { float f; unsigned u; } v; v.f = x;
    unsigned r = v.u + 0x7fff + ((v.u >> 16) & 1);  // RNE
    return (unsigned short)(r >> 16);
}

// pack two f32 -> u32 of 2x bf16 (lo=a, hi=b) via compiler intrinsic (RNE).
__device__ __forceinline__ unsigned pk_bf16(float a, float b) {
    __hip_bfloat162 h2 = __float22bfloat162_rn(float2{a, b});
    union { __hip_bfloat162 h; unsigned u; } u; u.h = h2;
    return u.u;
}

// monotone float<->uint map for atomicMax-based float max
__device__ __forceinline__ unsigned fmap(float x) {
    union { float f; unsigned u; } v; v.f = x;
    return (v.u & 0x80000000u) ? ~v.u : (v.u | 0x80000000u);
}
__device__ __forceinline__ float funmap(unsigned m) {
    union { float f; unsigned u; } v;
    v.u = (m & 0x80000000u) ? (m & 0x7fffffffu) : ~m;
    return v.f;
}

// async 16B global->LDS DMA
__device__ __forceinline__ void dma16(const void* g, void* l) {
    __builtin_amdgcn_global_load_lds((const __attribute__((address_space(1))) void*)g,
                                     (__attribute__((address_space(3))) void*)l, 16, 0, 0);
}

// ---- K1: h = inp @ W^T per (i-tile, head). Unchanged (verified; profile next round).
__global__ __launch_bounds__(256) void k_gemm(const float* __restrict__ inp,
                                              const float* __restrict__ W,
                                              const float* __restrict__ a_left,
                                              unsigned short* __restrict__ hbT,
                                              float* __restrict__ s,
                                              unsigned* __restrict__ smaxU) {
    __shared__ float As[64][69];
    __shared__ float Bs[64][69];
    __shared__ unsigned short h_st[64][72];
    __shared__ float s_red[64];

    const int t = threadIdx.x;
    const int bi = blockIdx.x;
    const int head = blockIdx.y;
    const int ty = t >> 4, tx = t & 15;
    const int lr = t >> 2;
    const int cq = (t & 3) * 16;

    float4 pa[4], pb[4];
    auto loadrk = [&](int k0) {
        const float* ip = &inp[(size_t)(bi * 64 + lr) * IN_F + k0 + cq];
        const float* wp = &W[(size_t)(head * 64 + lr) * IN_F + k0 + cq];
#pragma unroll
        for (int q = 0; q < 4; ++q) {
            pa[q] = *(const float4*)&ip[q * 4];
            pb[q] = *(const float4*)&wp[q * 4];
        }
    };
    loadrk(0);

    float acc[4][4] = {};
    for (int k0 = 0; k0 < IN_F; k0 += 64) {
        __syncthreads();
#pragma unroll
        for (int q = 0; q < 4; ++q)
#pragma unroll
            for (int j = 0; j < 4; ++j) {
                As[cq + q * 4 + j][lr] = ((const float*)&pa[q])[j];
                Bs[cq + q * 4 + j][lr] = ((const float*)&pb[q])[j];
            }
        __syncthreads();
        if (k0 + 64 < IN_F) loadrk(k0 + 64);
#pragma unroll
        for (int k = 0; k < 64; ++k) {
            float4 a4 = *(const float4*)&As[k][ty * 4];
            float4 b4 = *(const float4*)&Bs[k][tx * 4];
            float a[4] = {a4.x, a4.y, a4.z, a4.w};
            float b[4] = {b4.x, b4.y, b4.z, b4.w};
#pragma unroll
            for (int r = 0; r < 4; ++r)
#pragma unroll
                for (int c = 0; c < 4; ++c) acc[r][c] = fmaf(a[r], b[c], acc[r][c]);
        }
    }

    float aL[4];
#pragma unroll
    for (int c = 0; c < 4; ++c) aL[c] = a_left[head * D + tx * 4 + c];
#pragma unroll
    for (int r = 0; r < 4; ++r) {
        float sp = acc[r][0] * aL[0] + acc[r][1] * aL[1] + acc[r][2] * aL[2] + acc[r][3] * aL[3];
        sp += __shfl_xor(sp, 1); sp += __shfl_xor(sp, 2);
        sp += __shfl_xor(sp, 4); sp += __shfl_xor(sp, 8);
        if (tx == 0) {
            s[head * N + bi * 64 + ty * 4 + r] = sp;
            s_red[ty * 4 + r] = sp;
        }
    }
    __syncthreads();
    if (t < 64) {
        float m = s_red[t];
        for (int off = 32; off; off >>= 1) m = fmaxf(m, __shfl_down(m, off, 64));
        if (t == 0) atomicMax(&smaxU[head], fmap(m));
    }

#pragma unroll
    for (int r = 0; r < 4; ++r) {
        ushort4 v;
        v.x = f2bf(acc[r][0]); v.y = f2bf(acc[r][1]);
        v.z = f2bf(acc[r][2]); v.w = f2bf(acc[r][3]);
        *(ushort4*)&h_st[ty * 4 + r][tx * 4] = v;
    }
    __syncthreads();
    {
        const int d = t >> 2, iq = (t & 3) * 16;
        unsigned short us[16];
#pragma unroll
        for (int k = 0; k < 16; ++k) us[k] = h_st[iq + k][d];
        unsigned short* dst = &hbT[((size_t)(head * D + d)) * N + bi * 64 + iq];
#pragma unroll
        for (int q = 0; q < 4; ++q) {
            ushort4 v = {us[q * 4 + 0], us[q * 4 + 1], us[q * 4 + 2], us[q * 4 + 3]};
            *(ushort4*)&dst[q * 4] = v;
        }
    }
}

// ---- K2: per-row max of A
__global__ __launch_bounds__(256) void k_rowmax(const float* __restrict__ A,
                                                float* __restrict__ rmax) {
    int i = blockIdx.x;
    const float* row = &A[(size_t)i * N];
    float m = -1e30f;
    for (int j = threadIdx.x * 4; j < N; j += 256 * 4) {
        float4 v = *(const float4*)&row[j];
        m = fmaxf(fmaxf(fmaxf(m, v.x), fmaxf(v.y, v.z)), v.w);
    }
    for (int off = 32; off; off >>= 1) m = fmaxf(m, __shfl_down(m, off, 64));
    __shared__ float red[4];
    if ((threadIdx.x & 63) == 0) red[threadIdx.x >> 6] = m;
    __syncthreads();
    if (threadIdx.x == 0) rmax[i] = fmaxf(fmaxf(red[0], red[1]), fmaxf(red[2], red[3]));
}

// ---- K3 r6: block = (16 i-rows, 4 heads, full j). 512 thr = 8 waves;
// wave = (head wh, j-half jh): intra-block j-split -> cross-half reduce in LDS,
// NO global atomics, NO k_norm, NO out memset. hbT staged by swizzled DMA
// (r4-verified, 0 conflicts): per 32-j step 2jh x 4heads x 64d x 32j bf16 =
// 32KB, double-buffered = 64KB LDS -> 2 blocks/CU (4 waves/SIMD, 2x r3 TLP).
// A (lane-private) and s (quad-broadcast) are register-prefetched globals.
__global__ __launch_bounds__(512, 4) void k_attn(const float* __restrict__ A,
                                                 const unsigned short* __restrict__ hbT,
                                                 const float* __restrict__ s,
                                                 const unsigned* __restrict__ smaxU,
                                                 const float* __restrict__ rmax,
                                                 float* __restrict__ out) {
    __shared__ unsigned short hT_st[2][16384];  // 2 x 32KB; [0] reused as reduce buf

    const int t = threadIdx.x;
    const int bid = blockIdx.x;
    const int hg = bid & 1;            // head group (adjacent bids share A rows -> L3)
    const int i0 = (bid >> 1) * 16;

    const int lane = t & 63, wave = t >> 6;
    const int quad = lane >> 4, li = lane & 15;
    const int wh = wave & 3, jh = wave >> 2;
    const int head = hg * 4 + wh;
    const int row = i0 + li;
    const int jb = jh * 2048;
    const int NSTEP = 2048 / 32;       // 64

    // per-(row,head) softmax constants (exp2 domain)
    const float sr = s[head * N + row];
    const float sI = sr * LOG2E;
    const float mb = (leaky(sr + funmap(smaxU[head])) + rmax[row]) * LOG2E;

    // DMA sources, pre-swizzled (linear LDS dest; same XOR on read).
    // slot m in [0,2048): R=m>>2 in [0,512), sl=m&3.
    // R decode: jh_s=R>>8, (head,d): grow = hg*256 + (R&255); jbase = jh_s*2048.
    // LDS slot (R*4+sl) holds hbT[grow][jbase + it*32 + (sl^((R>>1)&3))*8 ..+7]
    const unsigned short* gH[4];
#pragma unroll
    for (int q = 0; q < 4; ++q) {
        int m = q * 512 + t, R = m >> 2, sl = m & 3;
        int grow = hg * 256 + (R & 255);
        int joff = (R >> 8) * 2048 + ((sl ^ ((R >> 1) & 3)) * 8);
        gH[q] = &hbT[(size_t)grow * N + joff];
    }

    const float* Ap = &A[(size_t)row * N + jb + quad * 8];
    const float* sp = &s[(size_t)head * N + jb + quad * 8];

    // prologue: stage step 0; prefetch A/s step 0
#pragma unroll
    for (int q = 0; q < 4; ++q) dma16(gH[q], &hT_st[0][(q * 512 + t) * 8]);
    float4 a0 = *(const float4*)&Ap[0], a1 = *(const float4*)&Ap[4];
    float4 s0 = *(const float4*)&sp[0], s1 = *(const float4*)&sp[4];
    __syncthreads();

    f32x4 acc[4] = {{0,0,0,0},{0,0,0,0},{0,0,0,0},{0,0,0,0}};
    float zs = 0.f;
    const int hsw = quad ^ ((li >> 1) & 3);   // read-side swizzle (per-lane const)
    const int Rb = jh * 256 + wh * 64;        // base staged-row for this wave

#pragma unroll 2
    for (int it = 0; it < NSTEP; ++it) {
        const int cur = it & 1;
        const bool more = (it + 1 < NSTEP);
        float4 na0, na1, ns0, ns1;
        if (more) {
            const int jn = (it + 1) * 32;
#pragma unroll
            for (int q = 0; q < 4; ++q)
                dma16(gH[q] + jn, &hT_st[cur ^ 1][(q * 512 + t) * 8]);
            na0 = *(const float4*)&Ap[jn]; na1 = *(const float4*)&Ap[jn + 4];
            ns0 = *(const float4*)&sp[jn]; ns1 = *(const float4*)&sp[jn + 4];
        }

        float av[8] = {a0.x, a0.y, a0.z, a0.w, a1.x, a1.y, a1.z, a1.w};
        float sv[8] = {s0.x, s0.y, s0.z, s0.w, s1.x, s1.y, s1.z, s1.w};
        union { bf16x8 v; unsigned u[4]; } P;
#pragma unroll
        for (int p = 0; p < 4; ++p) {
            float x0 = fmaf(sv[2 * p + 0], LOG2E, sI);   // (s_i + s_j)*log2e
            float x1 = fmaf(sv[2 * p + 1], LOG2E, sI);
            float w0 = __builtin_amdgcn_exp2f(fmaxf(x0, NEG * x0) + fmaf(av[2 * p + 0], LOG2E, -mb));
            float w1 = __builtin_amdgcn_exp2f(fmaxf(x1, NEG * x1) + fmaf(av[2 * p + 1], LOG2E, -mb));
            zs += w0 + w1;
            P.u[p] = pk_bf16(w0, w1);  // lo = even j, hi = odd j (verified r4/r5)
        }

        const unsigned short* bH = hT_st[cur];
#pragma unroll
        for (int db = 0; db < 4; ++db) {
            const int R = Rb + db * 16 + li;
            bf16x8 hf = *(const bf16x8*)&bH[(R * 4 + hsw) * 8];
            acc[db] = __builtin_amdgcn_mfma_f32_16x16x32_bf16(P.v, hf, acc[db], 0, 0, 0);
        }
        __syncthreads();
        if (more) { a0 = na0; a1 = na1; s0 = ns0; s1 = ns1; }
    }

    // cross-j-half reduce via LDS (stride 17 floats: conflict-free, 17.4KB in buf[0])
    float* red = (float*)&hT_st[0][0];
    if (jh == 1) {
        const int base = (wh * 64 + lane) * 17;
#pragma unroll
        for (int db = 0; db < 4; ++db)
#pragma unroll
            for (int r = 0; r < 4; ++r) red[base + db * 4 + r] = acc[db][r];
        red[base + 16] = zs;
    }
    __syncthreads();
    if (jh == 0) {
        const int base = (wh * 64 + lane) * 17;
#pragma unroll
        for (int db = 0; db < 4; ++db)
#pragma unroll
            for (int r = 0; r < 4; ++r) acc[db][r] += red[base + db * 4 + r];
        zs += red[base + 16];
        zs += __shfl_xor(zs, 16);
        zs += __shfl_xor(zs, 32);   // every lane: Z for row i0+li
#pragma unroll
        for (int r = 0; r < 4; ++r) {
            float zrow = __shfl(zs, quad * 4 + r, 64);  // lane li==quad*4+r holds Z
            float inv = 1.0f / zrow;
            float* op = &out[(size_t)(i0 + quad * 4 + r) * OUT_F + head * D];
#pragma unroll
            for (int db = 0; db < 4; ++db) op[db * 16 + li] = acc[db][r] * inv;
        }
    }
}

extern "C" void kernel_launch(void* const* d_in, const int* in_sizes, int n_in,
                              void* d_out, int out_size, void* d_ws, size_t ws_size,
                              hipStream_t stream) {
    const float* inp = (const float*)d_in[0];
    const float* A = (const float*)d_in[1];
    const float* W = (const float*)d_in[2];
    const float* a_left = (const float*)d_in[3];
    float* out = (float*)d_out;

    // ws layout: hbT (4MB) | s (128KB) | smaxU (32B) | rmax (16KB)
    unsigned short* hbT = (unsigned short*)d_ws;
    float* s = (float*)((char*)d_ws + (size_t)H * D * N * 2);
    unsigned* smaxU = (unsigned*)(s + (size_t)H * N);
    float* rmax = (float*)(smaxU + 8);

    hipMemsetAsync(smaxU, 0, 8 * sizeof(unsigned), stream);

    k_gemm<<<dim3(N / 64, H), 256, 0, stream>>>(inp, W, a_left, hbT, s, smaxU);
    k_rowmax<<<dim3(N), 256, 0, stream>>>(A, rmax);
    k_attn<<<dim3((N / 16) * 2), 512, 0, stream>>>(A, hbT, s, smaxU, rmax, out);
}

// Round 7
// 259.641 us; speedup vs baseline: 1.2213x; 1.0240x over previous
//
#include <hip/hip_runtime.h>
#include <hip/hip_bf16.h>
#include <math.h>

#define N 4096
#define IN_F 256
#define OUT_F 512
#define H 8
#define D 64
#define NEG 0.2f
#define LOG2E 1.44269504f

typedef __attribute__((ext_vector_type(8))) short bf16x8;
typedef __attribute__((ext_vector_type(4))) float f32x4;

__device__ __forceinline__ float leaky(float x) { return fmaxf(x, NEG * x); }

__device__ __forceinline__ unsigned short f2bf(float x) {
    union { float f; unsigned u; } v; v.f = x;
    unsigned r = v.u + 0x7fff + ((v.u >> 16) & 1);  // RNE
    return (unsigned short)(r >> 16);
}

// pack two f32 -> u32 of 2x bf16 (lo=a, hi=b) via compiler intrinsic (RNE).
__device__ __forceinline__ unsigned pk_bf16(float a, float b) {
    __hip_bfloat162 h2 = __float22bfloat162_rn(float2{a, b});
    union { __hip_bfloat162 h; unsigned u; } u; u.h = h2;
    return u.u;
}

// monotone float<->uint map for atomicMax-based float max
__device__ __forceinline__ unsigned fmap(float x) {
    union { float f; unsigned u; } v; v.f = x;
    return (v.u & 0x80000000u) ? ~v.u : (v.u | 0x80000000u);
}
__device__ __forceinline__ float funmap(unsigned m) {
    union { float f; unsigned u; } v;
    v.u = (m & 0x80000000u) ? (m & 0x7fffffffu) : ~m;
    return v.f;
}

// async 16B global->LDS DMA
__device__ __forceinline__ void dma16(const void* g, void* l) {
    __builtin_amdgcn_global_load_lds((const __attribute__((address_space(1))) void*)g,
                                     (__attribute__((address_space(3))) void*)l, 16, 0, 0);
}

// ---- K1: h = inp @ W^T per (i-tile, head). Unchanged (profile next round).
__global__ __launch_bounds__(256) void k_gemm(const float* __restrict__ inp,
                                              const float* __restrict__ W,
                                              const float* __restrict__ a_left,
                                              unsigned short* __restrict__ hbT,
                                              float* __restrict__ s,
                                              unsigned* __restrict__ smaxU) {
    __shared__ float As[64][69];
    __shared__ float Bs[64][69];
    __shared__ unsigned short h_st[64][72];
    __shared__ float s_red[64];

    const int t = threadIdx.x;
    const int bi = blockIdx.x;
    const int head = blockIdx.y;
    const int ty = t >> 4, tx = t & 15;
    const int lr = t >> 2;
    const int cq = (t & 3) * 16;

    float4 pa[4], pb[4];
    auto loadrk = [&](int k0) {
        const float* ip = &inp[(size_t)(bi * 64 + lr) * IN_F + k0 + cq];
        const float* wp = &W[(size_t)(head * 64 + lr) * IN_F + k0 + cq];
#pragma unroll
        for (int q = 0; q < 4; ++q) {
            pa[q] = *(const float4*)&ip[q * 4];
            pb[q] = *(const float4*)&wp[q * 4];
        }
    };
    loadrk(0);

    float acc[4][4] = {};
    for (int k0 = 0; k0 < IN_F; k0 += 64) {
        __syncthreads();
#pragma unroll
        for (int q = 0; q < 4; ++q)
#pragma unroll
            for (int j = 0; j < 4; ++j) {
                As[cq + q * 4 + j][lr] = ((const float*)&pa[q])[j];
                Bs[cq + q * 4 + j][lr] = ((const float*)&pb[q])[j];
            }
        __syncthreads();
        if (k0 + 64 < IN_F) loadrk(k0 + 64);
#pragma unroll
        for (int k = 0; k < 64; ++k) {
            float4 a4 = *(const float4*)&As[k][ty * 4];
            float4 b4 = *(const float4*)&Bs[k][tx * 4];
            float a[4] = {a4.x, a4.y, a4.z, a4.w};
            float b[4] = {b4.x, b4.y, b4.z, b4.w};
#pragma unroll
            for (int r = 0; r < 4; ++r)
#pragma unroll
                for (int c = 0; c < 4; ++c) acc[r][c] = fmaf(a[r], b[c], acc[r][c]);
        }
    }

    float aL[4];
#pragma unroll
    for (int c = 0; c < 4; ++c) aL[c] = a_left[head * D + tx * 4 + c];
#pragma unroll
    for (int r = 0; r < 4; ++r) {
        float sp = acc[r][0] * aL[0] + acc[r][1] * aL[1] + acc[r][2] * aL[2] + acc[r][3] * aL[3];
        sp += __shfl_xor(sp, 1); sp += __shfl_xor(sp, 2);
        sp += __shfl_xor(sp, 4); sp += __shfl_xor(sp, 8);
        if (tx == 0) {
            s[head * N + bi * 64 + ty * 4 + r] = sp;
            s_red[ty * 4 + r] = sp;
        }
    }
    __syncthreads();
    if (t < 64) {
        float m = s_red[t];
        for (int off = 32; off; off >>= 1) m = fmaxf(m, __shfl_down(m, off, 64));
        if (t == 0) atomicMax(&smaxU[head], fmap(m));
    }

#pragma unroll
    for (int r = 0; r < 4; ++r) {
        ushort4 v;
        v.x = f2bf(acc[r][0]); v.y = f2bf(acc[r][1]);
        v.z = f2bf(acc[r][2]); v.w = f2bf(acc[r][3]);
        *(ushort4*)&h_st[ty * 4 + r][tx * 4] = v;
    }
    __syncthreads();
    {
        const int d = t >> 2, iq = (t & 3) * 16;
        unsigned short us[16];
#pragma unroll
        for (int k = 0; k < 16; ++k) us[k] = h_st[iq + k][d];
        unsigned short* dst = &hbT[((size_t)(head * D + d)) * N + bi * 64 + iq];
#pragma unroll
        for (int q = 0; q < 4; ++q) {
            ushort4 v = {us[q * 4 + 0], us[q * 4 + 1], us[q * 4 + 2], us[q * 4 + 3]};
            *(ushort4*)&dst[q * 4] = v;
        }
    }
}

// ---- K2: per-row max of A
__global__ __launch_bounds__(256) void k_rowmax(const float* __restrict__ A,
                                                float* __restrict__ rmax) {
    int i = blockIdx.x;
    const float* row = &A[(size_t)i * N];
    float m = -1e30f;
    for (int j = threadIdx.x * 4; j < N; j += 256 * 4) {
        float4 v = *(const float4*)&row[j];
        m = fmaxf(fmaxf(fmaxf(m, v.x), fmaxf(v.y, v.z)), v.w);
    }
    for (int off = 32; off; off >>= 1) m = fmaxf(m, __shfl_down(m, off, 64));
    __shared__ float red[4];
    if ((threadIdx.x & 63) == 0) red[threadIdx.x >> 6] = m;
    __syncthreads();
    if (threadIdx.x == 0) rmax[i] = fmaxf(fmaxf(red[0], red[1]), fmaxf(red[2], red[3]));
}

// ---- K3 r7: same tiling as r6 (block = 16 i-rows x 4 heads x full j; 8 waves =
// (head, j-half); intra-block reduce; no global atomics). STRUCTURAL CHANGE:
// counted-vmcnt pipeline (T3/T4). Per step: B1 barrier (fence prior readers) ->
// issue DMA+reg loads for t+1 -> s_waitcnt vmcnt(8) (waits only tile t's 8
// OLDER ops; the 8 just-issued stay in flight ACROSS the barrier) -> B2 ->
// compute tile t. Raw s_barrier (no __syncthreads vmcnt(0) drain). Manual
// even/odd unroll gives two named reg sets (no copies -> no back-edge drain).
// Z is accumulated on the MFMA pipe via a ones-vector B operand (acc_z).
__global__ __launch_bounds__(512, 4) void k_attn(const float* __restrict__ A,
                                                 const unsigned short* __restrict__ hbT,
                                                 const float* __restrict__ s,
                                                 const unsigned* __restrict__ smaxU,
                                                 const float* __restrict__ rmax,
                                                 float* __restrict__ out) {
    __shared__ unsigned short hT_st[2][16384];  // 2 x 32KB; [0] reused as reduce buf

    const int t = threadIdx.x;
    const int bid = blockIdx.x;
    const int hg = bid & 1;
    const int i0 = (bid >> 1) * 16;

    const int lane = t & 63, wave = t >> 6;
    const int quad = lane >> 4, li = lane & 15;
    const int wh = wave & 3, jh = wave >> 2;
    const int head = hg * 4 + wh;
    const int row = i0 + li;
    const int jb = jh * 2048;
    const int NSTEP = 2048 / 32;  // 64 (even)

    // per-(row,head) softmax constants (exp2 domain)
    const float sr = s[head * N + row];
    const float sI = sr * LOG2E;
    const float mb = (leaky(sr + funmap(smaxU[head])) + rmax[row]) * LOG2E;

    // DMA sources, pre-swizzled (linear LDS dest; same XOR on read) — r6-verified.
    const unsigned short* gH[4];
#pragma unroll
    for (int q = 0; q < 4; ++q) {
        int m = q * 512 + t, R = m >> 2, sl = m & 3;
        int grow = hg * 256 + (R & 255);
        int joff = (R >> 8) * 2048 + ((sl ^ ((R >> 1) & 3)) * 8);
        gH[q] = &hbT[(size_t)grow * N + joff];
    }

    const float* Ap = &A[(size_t)row * N + jb + quad * 8];
    const float* sp = &s[(size_t)head * N + jb + quad * 8];

    f32x4 acc[4] = {{0,0,0,0},{0,0,0,0},{0,0,0,0},{0,0,0,0}};
    f32x4 acc_z = {0, 0, 0, 0};
    float zdummy = 0.f; (void)zdummy;
    bf16x8 vones;
#pragma unroll
    for (int k = 0; k < 8; ++k) vones[k] = (short)0x3F80;  // bf16 1.0

    const int hsw = quad ^ ((li >> 1) & 3);
    const int Rb = jh * 256 + wh * 64;

    // compute one staged 32-j tile from regs (A0,A1 = A vals; S0,S1 = s vals)
    auto compute_tile = [&](const unsigned short* bH, float4 A0, float4 A1,
                            float4 S0, float4 S1) {
        float av[8] = {A0.x, A0.y, A0.z, A0.w, A1.x, A1.y, A1.z, A1.w};
        float sv[8] = {S0.x, S0.y, S0.z, S0.w, S1.x, S1.y, S1.z, S1.w};
        union { bf16x8 v; unsigned u[4]; } P;
#pragma unroll
        for (int p = 0; p < 4; ++p) {
            float x0 = fmaf(sv[2 * p + 0], LOG2E, sI);
            float x1 = fmaf(sv[2 * p + 1], LOG2E, sI);
            float w0 = __builtin_amdgcn_exp2f(fmaxf(x0, NEG * x0) + fmaf(av[2 * p + 0], LOG2E, -mb));
            float w1 = __builtin_amdgcn_exp2f(fmaxf(x1, NEG * x1) + fmaf(av[2 * p + 1], LOG2E, -mb));
            P.u[p] = pk_bf16(w0, w1);
        }
        acc_z = __builtin_amdgcn_mfma_f32_16x16x32_bf16(P.v, vones, acc_z, 0, 0, 0);
#pragma unroll
        for (int db = 0; db < 4; ++db) {
            const int R = Rb + db * 16 + li;
            bf16x8 hf = *(const bf16x8*)&bH[(R * 4 + hsw) * 8];
            acc[db] = __builtin_amdgcn_mfma_f32_16x16x32_bf16(P.v, hf, acc[db], 0, 0, 0);
        }
    };

    // prologue: DMA tile0 -> buf0, reg-load step0 into set E (no drain needed)
#pragma unroll
    for (int q = 0; q < 4; ++q) dma16(gH[q], &hT_st[0][(q * 512 + t) * 8]);
    float4 eA0 = *(const float4*)&Ap[0], eA1 = *(const float4*)&Ap[4];
    float4 eS0 = *(const float4*)&sp[0], eS1 = *(const float4*)&sp[4];
    float4 oA0, oA1, oS0, oS1;

#pragma unroll 1
    for (int itp = 0; itp < NSTEP / 2; ++itp) {
        const int itE = itp * 2;
        // ---- even phase: compute buf0/tile itE, prefetch tile itE+1 -> buf1, set O
        __builtin_amdgcn_s_barrier();                       // B1: prior readers done
        {
            const int jn = (itE + 1) * 32;                  // always < 2048
#pragma unroll
            for (int q = 0; q < 4; ++q) dma16(gH[q] + jn, &hT_st[1][(q * 512 + t) * 8]);
            oA0 = *(const float4*)&Ap[jn]; oA1 = *(const float4*)&Ap[jn + 4];
            oS0 = *(const float4*)&sp[jn]; oS1 = *(const float4*)&sp[jn + 4];
        }
        asm volatile("s_waitcnt vmcnt(8)" ::: "memory");    // tile itE's 8 older ops done
        __builtin_amdgcn_sched_barrier(0);
        __builtin_amdgcn_s_barrier();                       // B2: buf0 globally ready
        compute_tile(hT_st[0], eA0, eA1, eS0, eS1);

        // ---- odd phase: compute buf1/tile itE+1, prefetch tile itE+2 -> buf0, set E
        __builtin_amdgcn_s_barrier();                       // B1
        if (itE + 2 < NSTEP) {
            const int jn = (itE + 2) * 32;
#pragma unroll
            for (int q = 0; q < 4; ++q) dma16(gH[q] + jn, &hT_st[0][(q * 512 + t) * 8]);
            eA0 = *(const float4*)&Ap[jn]; eA1 = *(const float4*)&Ap[jn + 4];
            eS0 = *(const float4*)&sp[jn]; eS1 = *(const float4*)&sp[jn + 4];
            asm volatile("s_waitcnt vmcnt(8)" ::: "memory");
        } else {
            asm volatile("s_waitcnt vmcnt(0)" ::: "memory");
        }
        __builtin_amdgcn_sched_barrier(0);
        __builtin_amdgcn_s_barrier();                       // B2: buf1 globally ready
        compute_tile(hT_st[1], oA0, oA1, oS0, oS1);
    }

    // cross-j-half reduce via LDS (stride 21 floats, conflict-free; fits in buf[0..])
    __syncthreads();
    float* red = (float*)&hT_st[0][0];
    if (jh == 1) {
        const int base = (wh * 64 + lane) * 21;
#pragma unroll
        for (int db = 0; db < 4; ++db)
#pragma unroll
            for (int r = 0; r < 4; ++r) red[base + db * 4 + r] = acc[db][r];
#pragma unroll
        for (int r = 0; r < 4; ++r) red[base + 16 + r] = acc_z[r];
    }
    __syncthreads();
    if (jh == 0) {
        const int base = (wh * 64 + lane) * 21;
#pragma unroll
        for (int db = 0; db < 4; ++db)
#pragma unroll
            for (int r = 0; r < 4; ++r) acc[db][r] += red[base + db * 4 + r];
#pragma unroll
        for (int r = 0; r < 4; ++r) {
            const float zT = acc_z[r] + red[base + 16 + r];  // Z for row i0+quad*4+r
            const float inv = 1.0f / zT;
            float* op = &out[(size_t)(i0 + quad * 4 + r) * OUT_F + head * D];
#pragma unroll
            for (int db = 0; db < 4; ++db) op[db * 16 + li] = acc[db][r] * inv;
        }
    }
}

extern "C" void kernel_launch(void* const* d_in, const int* in_sizes, int n_in,
                              void* d_out, int out_size, void* d_ws, size_t ws_size,
                              hipStream_t stream) {
    const float* inp = (const float*)d_in[0];
    const float* A = (const float*)d_in[1];
    const float* W = (const float*)d_in[2];
    const float* a_left = (const float*)d_in[3];
    float* out = (float*)d_out;

    // ws layout: hbT (4MB) | s (128KB) | smaxU (32B) | rmax (16KB)
    unsigned short* hbT = (unsigned short*)d_ws;
    float* s = (float*)((char*)d_ws + (size_t)H * D * N * 2);
    unsigned* smaxU = (unsigned*)(s + (size_t)H * N);
    float* rmax = (float*)(smaxU + 8);

    hipMemsetAsync(smaxU, 0, 8 * sizeof(unsigned), stream);

    k_gemm<<<dim3(N / 64, H), 256, 0, stream>>>(inp, W, a_left, hbT, s, smaxU);
    k_rowmax<<<dim3(N), 256, 0, stream>>>(A, rmax);
    k_attn<<<dim3((N / 16) * 2), 512, 0, stream>>>(A, hbT, s, smaxU, rmax, out);
}

// Round 8
// 245.747 us; speedup vs baseline: 1.2903x; 1.0565x over previous
//
#include <hip/hip_runtime.h>
#include <hip/hip_bf16.h>
#include <math.h>

#define N 4096
#define IN_F 256
#define OUT_F 512
#define H 8
#define D 64
#define NEG 0.2f
#define LOG2E 1.44269504f

typedef __attribute__((ext_vector_type(8))) short bf16x8;
typedef __attribute__((ext_vector_type(4))) float f32x4;

__device__ __forceinline__ float leaky(float x) { return fmaxf(x, NEG * x); }

__device__ __forceinline__ unsigned short f2bf(float x) {
    union { float f; unsigned u; } v; v.f = x;
    unsigned r = v.u + 0x7fff + ((v.u >> 16) & 1);  // RNE
    return (unsigned short)(r >> 16);
}

// pack two f32 -> u32 of 2x bf16 (lo=a, hi=b) via compiler intrinsic (RNE).
__device__ __forceinline__ unsigned pk_bf16(float a, float b) {
    __hip_bfloat162 h2 = __float22bfloat162_rn(float2{a, b});
    union { __hip_bfloat162 h; unsigned u; } u; u.h = h2;
    return u.u;
}

// monotone float<->uint map for atomicMax-based float max
__device__ __forceinline__ unsigned fmap(float x) {
    union { float f; unsigned u; } v; v.f = x;
    return (v.u & 0x80000000u) ? ~v.u : (v.u | 0x80000000u);
}
__device__ __forceinline__ float funmap(unsigned m) {
    union { float f; unsigned u; } v;
    v.u = (m & 0x80000000u) ? (m & 0x7fffffffu) : ~m;
    return v.f;
}

// async 16B global->LDS DMA
__device__ __forceinline__ void dma16(const void* g, void* l) {
    __builtin_amdgcn_global_load_lds((const __attribute__((address_space(1))) void*)g,
                                     (__attribute__((address_space(3))) void*)l, 16, 0, 0);
}

// ---- K1: h = inp @ W^T per (i-tile, head). Unchanged.
__global__ __launch_bounds__(256) void k_gemm(const float* __restrict__ inp,
                                              const float* __restrict__ W,
                                              const float* __restrict__ a_left,
                                              unsigned short* __restrict__ hbT,
                                              float* __restrict__ s,
                                              unsigned* __restrict__ smaxU) {
    __shared__ float As[64][69];
    __shared__ float Bs[64][69];
    __shared__ unsigned short h_st[64][72];
    __shared__ float s_red[64];

    const int t = threadIdx.x;
    const int bi = blockIdx.x;
    const int head = blockIdx.y;
    const int ty = t >> 4, tx = t & 15;
    const int lr = t >> 2;
    const int cq = (t & 3) * 16;

    float4 pa[4], pb[4];
    auto loadrk = [&](int k0) {
        const float* ip = &inp[(size_t)(bi * 64 + lr) * IN_F + k0 + cq];
        const float* wp = &W[(size_t)(head * 64 + lr) * IN_F + k0 + cq];
#pragma unroll
        for (int q = 0; q < 4; ++q) {
            pa[q] = *(const float4*)&ip[q * 4];
            pb[q] = *(const float4*)&wp[q * 4];
        }
    };
    loadrk(0);

    float acc[4][4] = {};
    for (int k0 = 0; k0 < IN_F; k0 += 64) {
        __syncthreads();
#pragma unroll
        for (int q = 0; q < 4; ++q)
#pragma unroll
            for (int j = 0; j < 4; ++j) {
                As[cq + q * 4 + j][lr] = ((const float*)&pa[q])[j];
                Bs[cq + q * 4 + j][lr] = ((const float*)&pb[q])[j];
            }
        __syncthreads();
        if (k0 + 64 < IN_F) loadrk(k0 + 64);
#pragma unroll
        for (int k = 0; k < 64; ++k) {
            float4 a4 = *(const float4*)&As[k][ty * 4];
            float4 b4 = *(const float4*)&Bs[k][tx * 4];
            float a[4] = {a4.x, a4.y, a4.z, a4.w};
            float b[4] = {b4.x, b4.y, b4.z, b4.w};
#pragma unroll
            for (int r = 0; r < 4; ++r)
#pragma unroll
                for (int c = 0; c < 4; ++c) acc[r][c] = fmaf(a[r], b[c], acc[r][c]);
        }
    }

    float aL[4];
#pragma unroll
    for (int c = 0; c < 4; ++c) aL[c] = a_left[head * D + tx * 4 + c];
#pragma unroll
    for (int r = 0; r < 4; ++r) {
        float sp = acc[r][0] * aL[0] + acc[r][1] * aL[1] + acc[r][2] * aL[2] + acc[r][3] * aL[3];
        sp += __shfl_xor(sp, 1); sp += __shfl_xor(sp, 2);
        sp += __shfl_xor(sp, 4); sp += __shfl_xor(sp, 8);
        if (tx == 0) {
            s[head * N + bi * 64 + ty * 4 + r] = sp;
            s_red[ty * 4 + r] = sp;
        }
    }
    __syncthreads();
    if (t < 64) {
        float m = s_red[t];
        for (int off = 32; off; off >>= 1) m = fmaxf(m, __shfl_down(m, off, 64));
        if (t == 0) atomicMax(&smaxU[head], fmap(m));
    }

#pragma unroll
    for (int r = 0; r < 4; ++r) {
        ushort4 v;
        v.x = f2bf(acc[r][0]); v.y = f2bf(acc[r][1]);
        v.z = f2bf(acc[r][2]); v.w = f2bf(acc[r][3]);
        *(ushort4*)&h_st[ty * 4 + r][tx * 4] = v;
    }
    __syncthreads();
    {
        const int d = t >> 2, iq = (t & 3) * 16;
        unsigned short us[16];
#pragma unroll
        for (int k = 0; k < 16; ++k) us[k] = h_st[iq + k][d];
        unsigned short* dst = &hbT[((size_t)(head * D + d)) * N + bi * 64 + iq];
#pragma unroll
        for (int q = 0; q < 4; ++q) {
            ushort4 v = {us[q * 4 + 0], us[q * 4 + 1], us[q * 4 + 2], us[q * 4 + 3]};
            *(ushort4*)&dst[q * 4] = v;
        }
    }
}

// ---- K2: per-row max of A
__global__ __launch_bounds__(256) void k_rowmax(const float* __restrict__ A,
                                                float* __restrict__ rmax) {
    int i = blockIdx.x;
    const float* row = &A[(size_t)i * N];
    float m = -1e30f;
    for (int j = threadIdx.x * 4; j < N; j += 256 * 4) {
        float4 v = *(const float4*)&row[j];
        m = fmaxf(fmaxf(fmaxf(m, v.x), fmaxf(v.y, v.z)), v.w);
    }
    for (int off = 32; off; off >>= 1) m = fmaxf(m, __shfl_down(m, off, 64));
    __shared__ float red[4];
    if ((threadIdx.x & 63) == 0) red[threadIdx.x >> 6] = m;
    __syncthreads();
    if (threadIdx.x == 0) rmax[i] = fmaxf(fmaxf(red[0], red[1]), fmaxf(red[2], red[3]));
}

// ---- K3 r8: WAVE-PRIVATE async pipelines, ZERO barriers in the main loop.
// Tiling as r6/r7: block = 16 i-rows x 4 heads x full j; 8 waves = (head wh,
// j-half jh). KEY CHANGE: each wave's staged hbT slice (its head's 64 d-rows,
// its j-half) is disjoint -> each wave DMAs its OWN 4KB/step into its OWN LDS
// region and consumes it with per-wave counted vmcnt (depth-2). Producer ==
// consumer -> no s_barrier/__syncthreads until the final reduce. 4 independent
// wave-pipelines per SIMD hide all latency. LDS 64KB -> 2 blocks/CU.
__global__ __launch_bounds__(512, 4) void k_attn(const float* __restrict__ A,
                                                 const unsigned short* __restrict__ hbT,
                                                 const float* __restrict__ s,
                                                 const unsigned* __restrict__ smaxU,
                                                 const float* __restrict__ rmax,
                                                 float* __restrict__ out) {
    __shared__ unsigned short hT_st[2][16384];  // 2 bufs x (8 waves x 2048 ushorts)

    const int t = threadIdx.x;
    const int bid = blockIdx.x;
    const int hg = bid & 1;
    const int i0 = (bid >> 1) * 16;

    const int lane = t & 63, wave = t >> 6;
    const int quad = lane >> 4, li = lane & 15;
    const int wh = wave & 3, jh = wave >> 2;
    const int head = hg * 4 + wh;
    const int row = i0 + li;
    const int jb = jh * 2048;
    const int NSTEP = 2048 / 32;  // 64
    const int wbase = wave * 2048;  // ushort offset of this wave's LDS region

    // per-(row,head) softmax constants (exp2 domain)
    const float sr = s[head * N + row];
    const float sI = sr * LOG2E;
    const float mb = (leaky(sr + funmap(smaxU[head])) + rmax[row]) * LOG2E;

    // Per-wave DMA sources, pre-swizzled (linear LDS dest; same XOR on read).
    // Wave slot m = q*64 + lane in [0,256): Rloc = m>>2 in [0,64) = d-row of
    // this wave's head; sl = m&3. LDS slot m holds
    // hbT[head*64+Rloc][jb + jt + ((sl^((Rloc>>1)&3))*8) .. +8).
    const unsigned short* gH[4];
#pragma unroll
    for (int q = 0; q < 4; ++q) {
        int m = q * 64 + lane, Rloc = m >> 2, sl = m & 3;
        int grow = head * 64 + Rloc;
        int jcol = jb + ((sl ^ ((Rloc >> 1) & 3)) * 8);
        gH[q] = &hbT[(size_t)grow * N + jcol];
    }

    const float* Ap = &A[(size_t)row * N + jb + quad * 8];
    const float* sp = &s[(size_t)head * N + jb + quad * 8];

    f32x4 acc[4] = {{0,0,0,0},{0,0,0,0},{0,0,0,0},{0,0,0,0}};
    f32x4 acc_z = {0, 0, 0, 0};
    bf16x8 vones;
#pragma unroll
    for (int k = 0; k < 8; ++k) vones[k] = (short)0x3F80;  // bf16 1.0

    const int hsw = quad ^ ((li >> 1) & 3);  // read-side swizzle (per-lane const)

    auto issue_tile = [&](int buf, int jn) {
#pragma unroll
        for (int q = 0; q < 4; ++q)
            dma16(gH[q] + jn, &hT_st[buf][wbase + (q * 64 + lane) * 8]);
    };

    // compute one staged 32-j tile: ds_read own region + softmax weights + MFMA
    auto compute_tile = [&](int buf, float4 A0, float4 A1, float4 S0, float4 S1) {
        float av[8] = {A0.x, A0.y, A0.z, A0.w, A1.x, A1.y, A1.z, A1.w};
        float sv[8] = {S0.x, S0.y, S0.z, S0.w, S1.x, S1.y, S1.z, S1.w};
        union { bf16x8 v; unsigned u[4]; } P;
#pragma unroll
        for (int p = 0; p < 4; ++p) {
            float x0 = fmaf(sv[2 * p + 0], LOG2E, sI);
            float x1 = fmaf(sv[2 * p + 1], LOG2E, sI);
            float w0 = __builtin_amdgcn_exp2f(fmaxf(x0, NEG * x0) + fmaf(av[2 * p + 0], LOG2E, -mb));
            float w1 = __builtin_amdgcn_exp2f(fmaxf(x1, NEG * x1) + fmaf(av[2 * p + 1], LOG2E, -mb));
            P.u[p] = pk_bf16(w0, w1);
        }
        acc_z = __builtin_amdgcn_mfma_f32_16x16x32_bf16(P.v, vones, acc_z, 0, 0, 0);
        const unsigned short* bH = &hT_st[buf][wbase];
#pragma unroll
        for (int db = 0; db < 4; ++db) {
            const int d = db * 16 + li;
            bf16x8 hf = *(const bf16x8*)&bH[(d * 4 + hsw) * 8];
            acc[db] = __builtin_amdgcn_mfma_f32_16x16x32_bf16(P.v, hf, acc[db], 0, 0, 0);
        }
    };

    // prologue: issue tiles 0 (buf0, regs E) and 1 (buf1, regs O); 16 VMEM in flight
    issue_tile(0, 0);
    float4 eA0 = *(const float4*)&Ap[0], eA1 = *(const float4*)&Ap[4];
    float4 eS0 = *(const float4*)&sp[0], eS1 = *(const float4*)&sp[4];
    issue_tile(1, 32);
    float4 oA0 = *(const float4*)&Ap[32], oA1 = *(const float4*)&Ap[36];
    float4 oS0 = *(const float4*)&sp[32], oS1 = *(const float4*)&sp[36];

#pragma unroll 1
    for (int itp = 0; itp < NSTEP / 2; ++itp) {
        // ---- even tile t = 2*itp (buf0, regs E)
        asm volatile("s_waitcnt vmcnt(8)" ::: "memory");  // tile t done; t+1 in flight
        __builtin_amdgcn_sched_barrier(0);
        compute_tile(0, eA0, eA1, eS0, eS1);
        if (itp < NSTEP / 2 - 1) {
            const int jn = (2 * itp + 2) * 32;
            issue_tile(0, jn);
            eA0 = *(const float4*)&Ap[jn]; eA1 = *(const float4*)&Ap[jn + 4];
            eS0 = *(const float4*)&sp[jn]; eS1 = *(const float4*)&sp[jn + 4];
        }
        // ---- odd tile t+1 (buf1, regs O)
        if (itp < NSTEP / 2 - 1) {
            asm volatile("s_waitcnt vmcnt(8)" ::: "memory");
        } else {
            asm volatile("s_waitcnt vmcnt(0)" ::: "memory");
        }
        __builtin_amdgcn_sched_barrier(0);
        compute_tile(1, oA0, oA1, oS0, oS1);
        if (itp < NSTEP / 2 - 1) {
            const int jn = (2 * itp + 3) * 32;
            issue_tile(1, jn);
            oA0 = *(const float4*)&Ap[jn]; oA1 = *(const float4*)&Ap[jn + 4];
            oS0 = *(const float4*)&sp[jn]; oS1 = *(const float4*)&sp[jn + 4];
        }
    }

    // cross-j-half reduce via LDS (stride 21 floats, conflict-free; fits buf[0..])
    __syncthreads();
    float* red = (float*)&hT_st[0][0];
    if (jh == 1) {
        const int base = (wh * 64 + lane) * 21;
#pragma unroll
        for (int db = 0; db < 4; ++db)
#pragma unroll
            for (int r = 0; r < 4; ++r) red[base + db * 4 + r] = acc[db][r];
#pragma unroll
        for (int r = 0; r < 4; ++r) red[base + 16 + r] = acc_z[r];
    }
    __syncthreads();
    if (jh == 0) {
        const int base = (wh * 64 + lane) * 21;
#pragma unroll
        for (int db = 0; db < 4; ++db)
#pragma unroll
            for (int r = 0; r < 4; ++r) acc[db][r] += red[base + db * 4 + r];
#pragma unroll
        for (int r = 0; r < 4; ++r) {
            const float zT = acc_z[r] + red[base + 16 + r];  // Z for row i0+quad*4+r
            const float inv = 1.0f / zT;
            float* op = &out[(size_t)(i0 + quad * 4 + r) * OUT_F + head * D];
#pragma unroll
            for (int db = 0; db < 4; ++db) op[db * 16 + li] = acc[db][r] * inv;
        }
    }
}

extern "C" void kernel_launch(void* const* d_in, const int* in_sizes, int n_in,
                              void* d_out, int out_size, void* d_ws, size_t ws_size,
                              hipStream_t stream) {
    const float* inp = (const float*)d_in[0];
    const float* A = (const float*)d_in[1];
    const float* W = (const float*)d_in[2];
    const float* a_left = (const float*)d_in[3];
    float* out = (float*)d_out;

    // ws layout: hbT (4MB) | s (128KB) | smaxU (32B) | rmax (16KB)
    unsigned short* hbT = (unsigned short*)d_ws;
    float* s = (float*)((char*)d_ws + (size_t)H * D * N * 2);
    unsigned* smaxU = (unsigned*)(s + (size_t)H * N);
    float* rmax = (float*)(smaxU + 8);

    hipMemsetAsync(smaxU, 0, 8 * sizeof(unsigned), stream);

    k_gemm<<<dim3(N / 64, H), 256, 0, stream>>>(inp, W, a_left, hbT, s, smaxU);
    k_rowmax<<<dim3(N), 256, 0, stream>>>(A, rmax);
    k_attn<<<dim3((N / 16) * 2), 512, 0, stream>>>(A, hbT, s, smaxU, rmax, out);
}

// Round 9
// 244.655 us; speedup vs baseline: 1.2961x; 1.0045x over previous
//
#include <hip/hip_runtime.h>
#include <hip/hip_bf16.h>
#include <math.h>

#define N 4096
#define IN_F 256
#define OUT_F 512
#define H 8
#define D 64
#define NEG 0.2f
#define LOG2E 1.44269504f

typedef __attribute__((ext_vector_type(8))) short bf16x8;
typedef __attribute__((ext_vector_type(4))) float f32x4;

__device__ __forceinline__ float leaky(float x) { return fmaxf(x, NEG * x); }

__device__ __forceinline__ unsigned short f2bf(float x) {
    union { float f; unsigned u; } v; v.f = x;
    unsigned r = v.u + 0x7fff + ((v.u >> 16) & 1);  // RNE
    return (unsigned short)(r >> 16);
}

// pack two f32 -> u32 of 2x bf16 (lo=a, hi=b) via compiler intrinsic (RNE).
__device__ __forceinline__ unsigned pk_bf16(float a, float b) {
    __hip_bfloat162 h2 = __float22bfloat162_rn(float2{a, b});
    union { __hip_bfloat162 h; unsigned u; } u; u.h = h2;
    return u.u;
}

// monotone float<->uint map for atomicMax-based float max
__device__ __forceinline__ unsigned fmap(float x) {
    union { float f; unsigned u; } v; v.f = x;
    return (v.u & 0x80000000u) ? ~v.u : (v.u | 0x80000000u);
}
__device__ __forceinline__ float funmap(unsigned m) {
    union { float f; unsigned u; } v;
    v.u = (m & 0x80000000u) ? (m & 0x7fffffffu) : ~m;
    return v.f;
}

// async 16B global->LDS DMA
__device__ __forceinline__ void dma16(const void* g, void* l) {
    __builtin_amdgcn_global_load_lds((const __attribute__((address_space(1))) void*)g,
                                     (__attribute__((address_space(3))) void*)l, 16, 0, 0);
}

// ---- K1: h = inp @ W^T per (i-tile, head). Unchanged.
__global__ __launch_bounds__(256) void k_gemm(const float* __restrict__ inp,
                                              const float* __restrict__ W,
                                              const float* __restrict__ a_left,
                                              unsigned short* __restrict__ hbT,
                                              float* __restrict__ s,
                                              unsigned* __restrict__ smaxU) {
    __shared__ float As[64][69];
    __shared__ float Bs[64][69];
    __shared__ unsigned short h_st[64][72];
    __shared__ float s_red[64];

    const int t = threadIdx.x;
    const int bi = blockIdx.x;
    const int head = blockIdx.y;
    const int ty = t >> 4, tx = t & 15;
    const int lr = t >> 2;
    const int cq = (t & 3) * 16;

    float4 pa[4], pb[4];
    auto loadrk = [&](int k0) {
        const float* ip = &inp[(size_t)(bi * 64 + lr) * IN_F + k0 + cq];
        const float* wp = &W[(size_t)(head * 64 + lr) * IN_F + k0 + cq];
#pragma unroll
        for (int q = 0; q < 4; ++q) {
            pa[q] = *(const float4*)&ip[q * 4];
            pb[q] = *(const float4*)&wp[q * 4];
        }
    };
    loadrk(0);

    float acc[4][4] = {};
    for (int k0 = 0; k0 < IN_F; k0 += 64) {
        __syncthreads();
#pragma unroll
        for (int q = 0; q < 4; ++q)
#pragma unroll
            for (int j = 0; j < 4; ++j) {
                As[cq + q * 4 + j][lr] = ((const float*)&pa[q])[j];
                Bs[cq + q * 4 + j][lr] = ((const float*)&pb[q])[j];
            }
        __syncthreads();
        if (k0 + 64 < IN_F) loadrk(k0 + 64);
#pragma unroll
        for (int k = 0; k < 64; ++k) {
            float4 a4 = *(const float4*)&As[k][ty * 4];
            float4 b4 = *(const float4*)&Bs[k][tx * 4];
            float a[4] = {a4.x, a4.y, a4.z, a4.w};
            float b[4] = {b4.x, b4.y, b4.z, b4.w};
#pragma unroll
            for (int r = 0; r < 4; ++r)
#pragma unroll
                for (int c = 0; c < 4; ++c) acc[r][c] = fmaf(a[r], b[c], acc[r][c]);
        }
    }

    float aL[4];
#pragma unroll
    for (int c = 0; c < 4; ++c) aL[c] = a_left[head * D + tx * 4 + c];
#pragma unroll
    for (int r = 0; r < 4; ++r) {
        float sp = acc[r][0] * aL[0] + acc[r][1] * aL[1] + acc[r][2] * aL[2] + acc[r][3] * aL[3];
        sp += __shfl_xor(sp, 1); sp += __shfl_xor(sp, 2);
        sp += __shfl_xor(sp, 4); sp += __shfl_xor(sp, 8);
        if (tx == 0) {
            s[head * N + bi * 64 + ty * 4 + r] = sp;
            s_red[ty * 4 + r] = sp;
        }
    }
    __syncthreads();
    if (t < 64) {
        float m = s_red[t];
        for (int off = 32; off; off >>= 1) m = fmaxf(m, __shfl_down(m, off, 64));
        if (t == 0) atomicMax(&smaxU[head], fmap(m));
    }

#pragma unroll
    for (int r = 0; r < 4; ++r) {
        ushort4 v;
        v.x = f2bf(acc[r][0]); v.y = f2bf(acc[r][1]);
        v.z = f2bf(acc[r][2]); v.w = f2bf(acc[r][3]);
        *(ushort4*)&h_st[ty * 4 + r][tx * 4] = v;
    }
    __syncthreads();
    {
        const int d = t >> 2, iq = (t & 3) * 16;
        unsigned short us[16];
#pragma unroll
        for (int k = 0; k < 16; ++k) us[k] = h_st[iq + k][d];
        unsigned short* dst = &hbT[((size_t)(head * D + d)) * N + bi * 64 + iq];
#pragma unroll
        for (int q = 0; q < 4; ++q) {
            ushort4 v = {us[q * 4 + 0], us[q * 4 + 1], us[q * 4 + 2], us[q * 4 + 3]};
            *(ushort4*)&dst[q * 4] = v;
        }
    }
}

// ---- K2: per-row max of A
__global__ __launch_bounds__(256) void k_rowmax(const float* __restrict__ A,
                                                float* __restrict__ rmax) {
    int i = blockIdx.x;
    const float* row = &A[(size_t)i * N];
    float m = -1e30f;
    for (int j = threadIdx.x * 4; j < N; j += 256 * 4) {
        float4 v = *(const float4*)&row[j];
        m = fmaxf(fmaxf(fmaxf(m, v.x), fmaxf(v.y, v.z)), v.w);
    }
    for (int off = 32; off; off >>= 1) m = fmaxf(m, __shfl_down(m, off, 64));
    __shared__ float red[4];
    if ((threadIdx.x & 63) == 0) red[threadIdx.x >> 6] = m;
    __syncthreads();
    if (threadIdx.x == 0) rmax[i] = fmaxf(fmaxf(red[0], red[1]), fmaxf(red[2], red[3]));
}

// ---- K3 r9: wave-private zero-barrier pipelines (r8) + DEEPER A/s prefetch.
// Streams have different latencies: hbT DMA hits L2 (~250cy) -> depth-2 LDS
// double-buffer is enough; A comes from HBM/L3 (~600-900cy; FETCH shows A is
// NOT L3-resident) -> its reg loads now use 4 named sets with issue-ahead-2
// (~2 compute-steps > 1000cy of cover). Steady state per step t:
//   issue dma(t+1) [4 ops] ; issue As(t+2) [4 ops] ; vmcnt(8) ; compute t.
// vmcnt(8) = the 8 just-issued ops; everything older (dma(t), As(t), As(t+1))
// is retired. Unroll x4 keeps set/buf indices compile-time (no scratch).
__global__ __launch_bounds__(512, 4) void k_attn(const float* __restrict__ A,
                                                 const unsigned short* __restrict__ hbT,
                                                 const float* __restrict__ s,
                                                 const unsigned* __restrict__ smaxU,
                                                 const float* __restrict__ rmax,
                                                 float* __restrict__ out) {
    __shared__ unsigned short hT_st[2][16384];  // 2 bufs x (8 waves x 2048 ushorts)

    const int t = threadIdx.x;
    const int bid = blockIdx.x;
    const int hg = bid & 1;
    const int i0 = (bid >> 1) * 16;

    const int lane = t & 63, wave = t >> 6;
    const int quad = lane >> 4, li = lane & 15;
    const int wh = wave & 3, jh = wave >> 2;
    const int head = hg * 4 + wh;
    const int row = i0 + li;
    const int jb = jh * 2048;
    const int NSTEP = 2048 / 32;   // 64
    const int wbase = wave * 2048; // ushort offset of this wave's LDS region

    // per-(row,head) softmax constants (exp2 domain)
    const float sr = s[head * N + row];
    const float sI = sr * LOG2E;
    const float mb = (leaky(sr + funmap(smaxU[head])) + rmax[row]) * LOG2E;

    // Per-wave DMA sources, pre-swizzled (linear LDS dest; same XOR on read).
    const unsigned short* gH[4];
#pragma unroll
    for (int q = 0; q < 4; ++q) {
        int m = q * 64 + lane, Rloc = m >> 2, sl = m & 3;
        int grow = head * 64 + Rloc;
        int jcol = jb + ((sl ^ ((Rloc >> 1) & 3)) * 8);
        gH[q] = &hbT[(size_t)grow * N + jcol];
    }

    const float* Ap = &A[(size_t)row * N + jb + quad * 8];
    const float* sp = &s[(size_t)head * N + jb + quad * 8];

    f32x4 acc[4] = {{0,0,0,0},{0,0,0,0},{0,0,0,0},{0,0,0,0}};
    f32x4 acc_z = {0, 0, 0, 0};
    bf16x8 vones;
#pragma unroll
    for (int k = 0; k < 8; ++k) vones[k] = (short)0x3F80;  // bf16 1.0

    const int hsw = quad ^ ((li >> 1) & 3);  // read-side swizzle (per-lane const)

    auto issue_tile = [&](int buf, int jn) {
#pragma unroll
        for (int q = 0; q < 4; ++q)
            dma16(gH[q] + jn, &hT_st[buf][wbase + (q * 64 + lane) * 8]);
    };

    // A/s register pipeline: 4 sets, always indexed with compile-time constants
    float4 rA0[4], rA1[4], rS0[4], rS1[4];
#define LOAD_AS(SET, JN)                                                   \
    do {                                                                   \
        rA0[SET] = *(const float4*)&Ap[(JN)];                              \
        rA1[SET] = *(const float4*)&Ap[(JN) + 4];                          \
        rS0[SET] = *(const float4*)&sp[(JN)];                              \
        rS1[SET] = *(const float4*)&sp[(JN) + 4];                          \
    } while (0)

    // compute one staged 32-j tile
    auto compute_tile = [&](int buf, float4 A0, float4 A1, float4 S0, float4 S1) {
        float av[8] = {A0.x, A0.y, A0.z, A0.w, A1.x, A1.y, A1.z, A1.w};
        float sv[8] = {S0.x, S0.y, S0.z, S0.w, S1.x, S1.y, S1.z, S1.w};
        union { bf16x8 v; unsigned u[4]; } P;
#pragma unroll
        for (int p = 0; p < 4; ++p) {
            float x0 = fmaf(sv[2 * p + 0], LOG2E, sI);
            float x1 = fmaf(sv[2 * p + 1], LOG2E, sI);
            float w0 = __builtin_amdgcn_exp2f(fmaxf(x0, NEG * x0) + fmaf(av[2 * p + 0], LOG2E, -mb));
            float w1 = __builtin_amdgcn_exp2f(fmaxf(x1, NEG * x1) + fmaf(av[2 * p + 1], LOG2E, -mb));
            P.u[p] = pk_bf16(w0, w1);
        }
        acc_z = __builtin_amdgcn_mfma_f32_16x16x32_bf16(P.v, vones, acc_z, 0, 0, 0);
        const unsigned short* bH = &hT_st[buf][wbase];
#pragma unroll
        for (int db = 0; db < 4; ++db) {
            const int d = db * 16 + li;
            bf16x8 hf = *(const bf16x8*)&bH[(d * 4 + hsw) * 8];
            acc[db] = __builtin_amdgcn_mfma_f32_16x16x32_bf16(P.v, hf, acc[db], 0, 0, 0);
        }
    };

    // prologue: dma(0)->buf0; As(0)->set0; As(1)->set1
    issue_tile(0, 0);
    LOAD_AS(0, 0);
    LOAD_AS(1, 32);

#pragma unroll 1
    for (int itp = 0; itp < NSTEP / 4; ++itp) {
#pragma unroll
        for (int u = 0; u < 4; ++u) {
            const int t4 = itp * 4 + u;
            if (t4 + 1 < NSTEP) issue_tile((u + 1) & 1, (t4 + 1) * 32);
            if (t4 + 2 < NSTEP) {
                const int jn = (t4 + 2) * 32;
                switch ((u + 2) & 3) {  // compile-time per unrolled instance
                    case 0: LOAD_AS(0, jn); break;
                    case 1: LOAD_AS(1, jn); break;
                    case 2: LOAD_AS(2, jn); break;
                    case 3: LOAD_AS(3, jn); break;
                }
            }
            if (t4 == NSTEP - 1) {
                asm volatile("s_waitcnt vmcnt(0)" ::: "memory");
            } else {
                asm volatile("s_waitcnt vmcnt(8)" ::: "memory");
            }
            __builtin_amdgcn_sched_barrier(0);
            compute_tile(u & 1, rA0[u], rA1[u], rS0[u], rS1[u]);
        }
    }
#undef LOAD_AS

    // cross-j-half reduce via LDS (stride 21 floats, conflict-free)
    __syncthreads();
    float* red = (float*)&hT_st[0][0];
    if (jh == 1) {
        const int base = (wh * 64 + lane) * 21;
#pragma unroll
        for (int db = 0; db < 4; ++db)
#pragma unroll
            for (int r = 0; r < 4; ++r) red[base + db * 4 + r] = acc[db][r];
#pragma unroll
        for (int r = 0; r < 4; ++r) red[base + 16 + r] = acc_z[r];
    }
    __syncthreads();
    if (jh == 0) {
        const int base = (wh * 64 + lane) * 21;
#pragma unroll
        for (int db = 0; db < 4; ++db)
#pragma unroll
            for (int r = 0; r < 4; ++r) acc[db][r] += red[base + db * 4 + r];
#pragma unroll
        for (int r = 0; r < 4; ++r) {
            const float zT = acc_z[r] + red[base + 16 + r];  // Z for row i0+quad*4+r
            const float inv = 1.0f / zT;
            float* op = &out[(size_t)(i0 + quad * 4 + r) * OUT_F + head * D];
#pragma unroll
            for (int db = 0; db < 4; ++db) op[db * 16 + li] = acc[db][r] * inv;
        }
    }
}

extern "C" void kernel_launch(void* const* d_in, const int* in_sizes, int n_in,
                              void* d_out, int out_size, void* d_ws, size_t ws_size,
                              hipStream_t stream) {
    const float* inp = (const float*)d_in[0];
    const float* A = (const float*)d_in[1];
    const float* W = (const float*)d_in[2];
    const float* a_left = (const float*)d_in[3];
    float* out = (float*)d_out;

    // ws layout: hbT (4MB) | s (128KB) | smaxU (32B) | rmax (16KB)
    unsigned short* hbT = (unsigned short*)d_ws;
    float* s = (float*)((char*)d_ws + (size_t)H * D * N * 2);
    unsigned* smaxU = (unsigned*)(s + (size_t)H * N);
    float* rmax = (float*)(smaxU + 8);

    hipMemsetAsync(smaxU, 0, 8 * sizeof(unsigned), stream);

    k_gemm<<<dim3(N / 64, H), 256, 0, stream>>>(inp, W, a_left, hbT, s, smaxU);
    k_rowmax<<<dim3(N), 256, 0, stream>>>(A, rmax);
    k_attn<<<dim3((N / 16) * 2), 512, 0, stream>>>(A, hbT, s, smaxU, rmax, out);
}